// Round 3
// baseline (259.987 us; speedup 1.0000x reference)
//
#include <hip/hip_runtime.h>

#define NCLASS 5
#define NB 2
#define VOX (96*160*160)   // 2,457,600 voxels per batch item
#define V4  (VOX/4)        // 614,400 float4 packs per batch item

// Workspace layout (floats):
//   [0,50)    : S sums   idx = (b*5 + k)*5 + c
//   [50,100)  : T sums   idx = 50 + (b*5 + k)*5 + c
//   [100,110) : counts   idx = 100 + b*5 + k
#define WS_FLOATS 110

__global__ __launch_bounds__(256)
void kd_partial(const float* __restrict__ src, const float* __restrict__ tgt,
                const int* __restrict__ gt, float* __restrict__ ws)
{
    const int nbPerB = gridDim.x >> 1;           // blocks per batch item
    const int b      = blockIdx.x / nbPerB;      // 0 or 1
    const int blk    = blockIdx.x - b * nbPerB;

    const float* sb = src + (size_t)b * NCLASS * VOX;
    const float* tb = tgt + (size_t)b * NCLASS * VOX;
    const int*   gb = gt  + (size_t)b * VOX;

    float accS[NCLASS][NCLASS];
    float accT[NCLASS][NCLASS];
    float cnt[NCLASS];
    #pragma unroll
    for (int k = 0; k < NCLASS; ++k) {
        cnt[k] = 0.f;
        #pragma unroll
        for (int c = 0; c < NCLASS; ++c) { accS[k][c] = 0.f; accT[k][c] = 0.f; }
    }

    const int tid    = blk * 256 + threadIdx.x;
    const int stride = nbPerB * 256;

    for (int i = tid; i < V4; i += stride) {
        const int4 g4 = ((const int4*)gb)[i];
        float4 s4[NCLASS], t4[NCLASS];
        #pragma unroll
        for (int c = 0; c < NCLASS; ++c) {
            s4[c] = ((const float4*)(sb + (size_t)c * VOX))[i];
            t4[c] = ((const float4*)(tb + (size_t)c * VOX))[i];
        }
        // Per voxel: predicated FMA into statically-indexed accumulators.
        #define DO_VOX(GK, COMP) {                                           \
            const int kv = (GK);                                             \
            _Pragma("unroll")                                                \
            for (int kk = 0; kk < NCLASS; ++kk) {                            \
                const float m = (kv == kk) ? 1.0f : 0.0f;                    \
                cnt[kk] += m;                                                \
                _Pragma("unroll")                                            \
                for (int c = 0; c < NCLASS; ++c) {                           \
                    accS[kk][c] = fmaf(m, s4[c].COMP, accS[kk][c]);          \
                    accT[kk][c] = fmaf(m, t4[c].COMP, accT[kk][c]);          \
                }                                                            \
            }                                                                \
        }
        DO_VOX(g4.x, x)
        DO_VOX(g4.y, y)
        DO_VOX(g4.z, z)
        DO_VOX(g4.w, w)
        #undef DO_VOX
    }

    // ---- block-level reduction: wave shuffle -> LDS -> global atomic ----
    __shared__ float lacc[55];
    const int lane = threadIdx.x & 63;
    if (threadIdx.x < 55) lacc[threadIdx.x] = 0.f;
    __syncthreads();

    #define WAVE_RED(VAL, IDX) {                                             \
        float v_ = (VAL);                                                    \
        _Pragma("unroll")                                                    \
        for (int off_ = 32; off_; off_ >>= 1) v_ += __shfl_xor(v_, off_);    \
        if (lane == 0) atomicAdd(&lacc[(IDX)], v_);                          \
    }
    #pragma unroll
    for (int k = 0; k < NCLASS; ++k) {
        #pragma unroll
        for (int c = 0; c < NCLASS; ++c) {
            WAVE_RED(accS[k][c], k * 5 + c);
            WAVE_RED(accT[k][c], 25 + k * 5 + c);
        }
        WAVE_RED(cnt[k], 50 + k);
    }
    #undef WAVE_RED
    __syncthreads();

    if (threadIdx.x < 55) {
        const int i = threadIdx.x;
        int gidx;
        if (i < 25)       gidx = b * 25 + i;                 // S
        else if (i < 50)  gidx = 50 + b * 25 + (i - 25);     // T
        else              gidx = 100 + b * 5 + (i - 50);     // counts
        atomicAdd(&ws[gidx], lacc[i]);
    }
}

__global__ void kd_final(const float* __restrict__ ws, float* __restrict__ out)
{
    if (threadIdx.x == 0 && blockIdx.x == 0) {
        double total = 0.0;
        for (int k = 0; k < NCLASS; ++k) {
            // NOTE: reference's nvox sums the one-hot over the BATCH axis too:
            // denom[k] is shared across both batch items.
            const double denom = (double)ws[100 + 0 * 5 + k]
                               + (double)ws[100 + 1 * 5 + k] + 1e-6;
            for (int b = 0; b < NB; ++b) {
                double sa[4], ta[4];
                for (int c = 0; c < 4; ++c) {
                    // classes 1..4, divided by denom, then by temperature 2.0
                    sa[c] = ((double)ws[(b * 5 + k) * 5 + (c + 1)] / denom) * 0.5;
                    ta[c] = ((double)ws[50 + (b * 5 + k) * 5 + (c + 1)] / denom) * 0.5;
                }
                double ms = sa[0], mt = ta[0];
                for (int c = 1; c < 4; ++c) {
                    if (sa[c] > ms) ms = sa[c];
                    if (ta[c] > mt) mt = ta[c];
                }
                double es = 0.0, et = 0.0;
                for (int c = 0; c < 4; ++c) { es += exp(sa[c] - ms); et += exp(ta[c] - mt); }
                const double lses = ms + log(es);
                const double lset = mt + log(et);
                for (int c = 0; c < 4; ++c) {
                    const double slp = sa[c] - lses;
                    const double tlp = ta[c] - lset;
                    total += exp(tlp) * (tlp - slp) + exp(slp) * (slp - tlp);
                }
            }
        }
        // total / (2 [sym avg] * batch=2 * mean over k=5) = total / 20
        out[0] = (float)(total / 20.0);
    }
}

extern "C" void kernel_launch(void* const* d_in, const int* in_sizes, int n_in,
                              void* d_out, int out_size, void* d_ws, size_t ws_size,
                              hipStream_t stream)
{
    const float* src = (const float*)d_in[0];
    const float* tgt = (const float*)d_in[1];
    const int*   gt  = (const int*)d_in[2];
    float* out = (float*)d_out;
    float* ws  = (float*)d_ws;

    hipMemsetAsync(ws, 0, WS_FLOATS * sizeof(float), stream);
    kd_partial<<<dim3(1024), dim3(256), 0, stream>>>(src, tgt, gt, ws);
    kd_final<<<dim3(1), dim3(64), 0, stream>>>(ws, out);
}